// Round 3
// baseline (8742.422 us; speedup 1.0000x reference)
//
#include <hip/hip_runtime.h>
#include <stdint.h>

// (B,S,V,H,O) = (64,1024,32000,1024,128). ALL float tensors are float32
// (per the reference); x is int32; output is float32. MFMA runs on bf16
// converted copies (W pre-packed into ws once per launch; xe/h converted
// on the fly). c kept in f32; gates accumulated in f32.
#define BB 64
#define SS 1024
#define HH 1024

typedef unsigned short u16;
typedef short bf8 __attribute__((ext_vector_type(8)));     // 8 bf16 = 4 VGPRs
typedef float f32x4 __attribute__((ext_vector_type(4)));

static __device__ __forceinline__ u16 f2bf(float f) {
    union { float f; uint32_t u; } v; v.f = f;
    uint32_t r = (v.u + 0x7fffu + ((v.u >> 16) & 1u)) >> 16;  // RNE
    return (u16)r;
}
static __device__ __forceinline__ float bf2f(u16 u) {
    union { uint32_t u; float f; } v; v.u = ((uint32_t)u) << 16; return v.f;
}

// ---------------------------------------------------------------------------
// Pre-pass 1: pack W_ih|W_hh (f32) -> Wpk (bf16) in MFMA B-fragment order.
// Chunk c = (ct*4 + q)*64 + kb  (ct=channel tile 0..63, q=gate 0..3, kb=K-block
// 0..63 over K=2048=[ih|hh]); inside a chunk: offset (quad*16+n)*8 + j, i.e.
// exactly lane*8+j, so the step kernel loads bv = Wpk[chunk*512 + lane*8].
// W row for (ct,q,n): row = q*1024 + ct*16 + n ; k = kb*32 + quad*8 + j.
__global__ __launch_bounds__(256) void pack_w(
    const float* __restrict__ Wih, const float* __restrict__ Whh,
    u16* __restrict__ Wpk)
{
    int t = blockIdx.x * 256 + threadIdx.x;       // 0 .. 1048575, 8 elems each
    int chunk = t >> 6;
    int quad  = (t & 63) >> 4;
    int n     = t & 15;
    int kb    = chunk & 63;
    int q     = (chunk >> 6) & 3;
    int ct    = chunk >> 8;
    int row   = q * HH + ct * 16 + n;
    int k     = kb * 32 + quad * 8;               // 0..2040
    const float* src = (kb < 32) ? (Wih + (size_t)row * HH + k)
                                 : (Whh + (size_t)row * HH + (k - HH));
    u16* dst = Wpk + (size_t)t * 8;
    #pragma unroll
    for (int j = 0; j < 8; ++j) dst[j] = f2bf(src[j]);
}

// Pre-pass 2: bsum = b_ih + b_hh (f32, 4096)
__global__ __launch_bounds__(256) void pack_bias(
    const float* __restrict__ bih, const float* __restrict__ bhh,
    float* __restrict__ bsum)
{
    int i = blockIdx.x * 256 + threadIdx.x;
    if (i < 4 * HH) bsum[i] = bih[i] + bhh[i];
}

#define ASTRIDE 2056

// One LSTM timestep. Grid 256 = bt(0..3) x ct(0..63); 256 threads = 4 waves.
// Wave q computes gate q's 16x16 tile over K=2048 with mfma_f32_16x16x32_bf16.
// HW-verified layouts: A[m=lane&15][k=quad*8+j] (m120); C/D col=lane&15,
// row=quad*4+reg (m89).
__global__ __launch_bounds__(256) void lstm_step(
    const int*   __restrict__ x,      // [B,S] int32
    const float* __restrict__ emb,    // [V,H] f32
    const u16*   __restrict__ Wpk,    // packed bf16 weights (ws)
    const float* __restrict__ bsum,   // [4H] f32 (ws)
    const float* __restrict__ h0,     // [B,H] f32 (input, step 0 only)
    const float* __restrict__ c0,     // [B,H] f32 (input, step 0 only)
    const u16*   __restrict__ hsrc,   // [B,H] bf16 (ws, steps > 0)
    u16*         __restrict__ hdst,   // [B,H] bf16 (ws)
    float*       __restrict__ cbuf,   // [B,H] f32  (ws)
    int s)
{
    __shared__ u16   Ash[16 * ASTRIDE];   // A = [xe | h], 16 rows x 2048 bf16
    __shared__ float g4[4][16][17];

    const int tid = threadIdx.x;
    const int bt  = blockIdx.x >> 6;
    const int ct  = blockIdx.x & 63;

    // ---- Phase 1: stage A into LDS (convert f32 -> bf16 as needed) ----
    {
        const int r  = tid >> 4;          // local batch row 0..15
        const int li = tid & 15;
        const int b  = bt * 16 + r;
        const float* erow = emb + (size_t)x[(size_t)b * SS + s] * HH;
        u16* dst = Ash + r * ASTRIDE;
        #pragma unroll
        for (int p = 0; p < 16; ++p) {
            int e = (p * 16 + li) * 8;    // 0..2040, step 8
            if (e < HH) {                 // xe half: gather + convert
                const float* sp = erow + e;
                u16 tmp[8];
                #pragma unroll
                for (int j = 0; j < 8; ++j) tmp[j] = f2bf(sp[j]);
                *(bf8*)(dst + e) = *(bf8*)tmp;
            } else if (s == 0) {          // h half, step 0: h0 is f32
                const float* sp = h0 + (size_t)b * HH + (e - HH);
                u16 tmp[8];
                #pragma unroll
                for (int j = 0; j < 8; ++j) tmp[j] = f2bf(sp[j]);
                *(bf8*)(dst + e) = *(bf8*)tmp;
            } else {                      // h half: bf16 copy from ws
                *(bf8*)(dst + e) = *(const bf8*)(hsrc + (size_t)b * HH + (e - HH));
            }
        }
    }
    __syncthreads();

    // ---- Phase 2: wave q computes gate q's 16x16 tile, K = 2048 ----
    {
        const int q    = tid >> 6;
        const int lane = tid & 63;
        const int n    = lane & 15;
        const int quad = lane >> 4;

        const u16* ar = Ash + n * ASTRIDE + quad * 8;
        const u16* wr = Wpk + ((size_t)(ct * 4 + q) * 64) * 512 + lane * 8;

        f32x4 acc = {0.f, 0.f, 0.f, 0.f};
        #pragma unroll
        for (int kb = 0; kb < 64; ++kb) {
            bf8 av = *(const bf8*)(ar + kb * 32);
            bf8 bv = *(const bf8*)(wr + kb * 512);
            acc = __builtin_amdgcn_mfma_f32_16x16x32_bf16(av, bv, acc, 0, 0, 0);
        }
        #pragma unroll
        for (int r = 0; r < 4; ++r)
            g4[q][quad * 4 + r][n] = acc[r];
    }
    __syncthreads();

    // ---- Phase 3: nonlinearity + c/h update; thread owns one (b, ch) ----
    {
        const int m  = tid >> 4;
        const int j  = tid & 15;
        const int b  = bt * 16 + m;
        const int ch = ct * 16 + j;

        float gi = g4[0][m][j] + bsum[ch];
        float gf = g4[1][m][j] + bsum[HH + ch];
        float gg = g4[2][m][j] + bsum[2 * HH + ch];
        float go = g4[3][m][j] + bsum[3 * HH + ch];

        float ig = 1.f / (1.f + __expf(-gi));
        float fg = 1.f / (1.f + __expf(-gf));
        float gv = tanhf(gg);
        float og = 1.f / (1.f + __expf(-go));

        size_t idx = (size_t)b * HH + ch;
        float cp = (s == 0) ? c0[idx] : cbuf[idx];
        float cn = fg * cp + ig * gv;
        cbuf[idx] = cn;
        hdst[idx] = f2bf(og * tanhf(cn));
    }
}

// out[b][o] = h_last[b] . fc_W[o] + fc_b[o]; f32 output. Grid: 64 x 128.
__global__ __launch_bounds__(128) void fc_kernel(
    const u16*   __restrict__ h,      // [B,H] bf16 (ws)
    const float* __restrict__ fcW,    // [O,H] f32
    const float* __restrict__ fcb,    // [O]  f32
    float*       __restrict__ out)    // [B,O] f32
{
    int b = blockIdx.x;
    int o = threadIdx.x;
    const u16*   hp = h + (size_t)b * HH;
    const float* wp = fcW + (size_t)o * HH;
    float acc = 0.f;
    for (int k = 0; k < HH; k += 8) {
        bf8 hv = *(const bf8*)(hp + k);
        #pragma unroll
        for (int e = 0; e < 8; ++e)
            acc += bf2f((u16)hv[e]) * wp[k + e];
    }
    out[(size_t)b * 128 + o] = acc + fcb[o];
}

extern "C" void kernel_launch(void* const* d_in, const int* in_sizes, int n_in,
                              void* d_out, int out_size, void* d_ws, size_t ws_size,
                              hipStream_t stream) {
    const int*   x   = (const int*)d_in[0];
    const float* emb = (const float*)d_in[1];
    const float* Wih = (const float*)d_in[2];
    const float* Whh = (const float*)d_in[3];
    const float* bih = (const float*)d_in[4];
    const float* bhh = (const float*)d_in[5];
    const float* fcW = (const float*)d_in[6];
    const float* fcb = (const float*)d_in[7];
    const float* h0  = (const float*)d_in[8];
    const float* c0  = (const float*)d_in[9];

    // ws layout:
    //   Wpk  : 8 M bf16  = 16 MB   (packed weights)
    //   hbuf : 2 x 64 K bf16 = 256 KB (double-buffered h)
    //   cbuf : 64 K f32  = 256 KB
    //   bsum : 4 K  f32  = 16 KB
    char* w = (char*)d_ws;
    u16*   Wpk  = (u16*)w;                      w += (size_t)4 * HH * 2 * HH * sizeof(u16);
    u16*   hbuf = (u16*)w;                      w += (size_t)2 * BB * HH * sizeof(u16);
    float* cbuf = (float*)w;                    w += (size_t)BB * HH * sizeof(float);
    float* bsum = (float*)w;

    pack_w<<<4096, 256, 0, stream>>>(Wih, Whh, Wpk);
    pack_bias<<<16, 256, 0, stream>>>(bih, bhh, bsum);

    for (int s = 0; s < SS; ++s) {
        const u16* hs = hbuf + (size_t)(s & 1) * BB * HH;        // ignored at s==0
        u16*       hd = hbuf + (size_t)((s + 1) & 1) * BB * HH;
        lstm_step<<<256, 256, 0, stream>>>(x, emb, Wpk, bsum, h0, c0, hs, hd, cbuf, s);
    }
    // h_last is in parity (1023+1)&1 = 0.
    fc_kernel<<<BB, 128, 0, stream>>>(hbuf, fcW, fcb, (float*)d_out);
}